// Round 1
// 2925.660 us; speedup vs baseline: 1.1151x; 1.1151x over previous
//
#include <hip/hip_runtime.h>
#include <math.h>

#define NEGV (-100000.0f)
constexpr int Bn = 64, Sn = 512, En = 256, Hn = 256, HIDn = 512, Tn = 9;
constexpr int START_T = Tn - 2, STOP_T = Tn - 1;
constexpr int Mn = Bn * Sn; // 32768 rows

typedef unsigned int u32;
typedef unsigned short u16;
typedef unsigned long long u64;
typedef short short8 __attribute__((ext_vector_type(8)));
typedef float f32x4 __attribute__((ext_vector_type(4)));

__device__ __forceinline__ float sigf(float x) { return 1.0f / (1.0f + __expf(-x)); }
__device__ __forceinline__ float tanh_f(float x) { return 2.0f / (1.0f + __expf(-2.0f * x)) - 1.0f; }
__device__ __forceinline__ u16 f2bf(float f) {
  u32 u = __float_as_uint(f);
  return (u16)((u + 0x7fffu + ((u >> 16) & 1u)) >> 16);
}
__device__ __forceinline__ float bflo(u32 u) { return __uint_as_float(u << 16); }
__device__ __forceinline__ float bfhi(u32 u) { return __uint_as_float(u & 0xffff0000u); }
__device__ __forceinline__ float b2f(u16 v) { return __uint_as_float((u32)v << 16); }

// ---------------- prep: all weights to bf16 MFMA B-fragment order ----------------
// whh frags (recur):  wfrag[d][nq][ks][tau][lane][j]; tau=ub*4+gate; unit=nq*64+ub*16+(lane&15);
//                     row=gate*256+unit; k=ks*32+((lane>>4)&3)*8+j
// wih frags (gemm):   wifrag[d][nb][w][ks][lane][j]; n=nb*64+w*16+(lane&15); k=ks*32+((lane>>4)&3)*8+j
__global__ void prep_kernel(const float* __restrict__ wih0, const float* __restrict__ whh0,
                            const float* __restrict__ bih0, const float* __restrict__ bhh0,
                            const float* __restrict__ wih1, const float* __restrict__ whh1,
                            const float* __restrict__ bih1, const float* __restrict__ bhh1,
                            u16* __restrict__ wifrag0, u16* __restrict__ wifrag1,
                            u16* __restrict__ wfrag0, u16* __restrict__ wfrag1,
                            float* __restrict__ bias0, float* __restrict__ bias1) {
  int tid = blockIdx.x * blockDim.x + threadIdx.x;
  int nth = gridDim.x * blockDim.x;
  // wih0 frags: K=256, KS=8 -> 2*16*4*8*64*8 = 524288 u16
  for (int idx = tid; idx < 524288; idx += nth) {
    int j = idx & 7, lane = (idx >> 3) & 63, ks = (idx >> 9) & 7,
        w2 = (idx >> 12) & 3, nb = (idx >> 14) & 15, d = (idx >> 18) & 1;
    int n = nb * 64 + w2 * 16 + (lane & 15);
    int k = ks * 32 + ((lane >> 4) & 3) * 8 + j;
    wifrag0[idx] = f2bf(wih0[(d * 1024 + n) * 256 + k]);
  }
  // wih1 frags: K=512, KS=16 -> 2*16*4*16*64*8 = 1048576 u16
  for (int idx = tid; idx < 1048576; idx += nth) {
    int j = idx & 7, lane = (idx >> 3) & 63, ks = (idx >> 9) & 15,
        w2 = (idx >> 13) & 3, nb = (idx >> 15) & 15, d = (idx >> 19) & 1;
    int n = nb * 64 + w2 * 16 + (lane & 15);
    int k = ks * 32 + ((lane >> 4) & 3) * 8 + j;
    wifrag1[idx] = f2bf(wih1[(d * 1024 + n) * 512 + k]);
  }
  // whh frags (unchanged layout from round 10)
  for (int idx = tid; idx < 524288; idx += nth) {
    int j = idx & 7, lane = (idx >> 3) & 63, tau = (idx >> 9) & 15,
        ks = (idx >> 13) & 7, nq = (idx >> 16) & 3, d = (idx >> 18) & 1;
    int ub = tau >> 2, gate = tau & 3;
    int unit = nq * 64 + ub * 16 + (lane & 15);
    int row = gate * 256 + unit;
    int k = ks * 32 + ((lane >> 4) & 3) * 8 + j;
    wfrag0[idx] = f2bf(whh0[(d * 1024 + row) * 256 + k]);
    wfrag1[idx] = f2bf(whh1[(d * 1024 + row) * 256 + k]);
  }
  for (int idx = tid; idx < 2 * 1024; idx += nth) {
    bias0[idx] = bih0[idx] + bhh0[idx];
    bias1[idx] = bih1[idx] + bhh1[idx];
  }
}

// ---------------- MFMA input-projection GEMM -> gate-packed gx2[dir][m][unit][gate] ----------------
// Block: 256 thr, grid (Mn/64, 2). A (64 x K bf16) staged in LDS once; 16 n-tiles, no inner barriers.
template <int KS, bool GATHER>   // KS = K/32
__global__ __launch_bounds__(256) void gemm_ih(
    const void* __restrict__ xsrc_v,   // GATHER: fp32 emb; else bf16 rows [M][512]
    const int* __restrict__ sent,
    const uint4* __restrict__ wifrag,  // [2][16][4][KS][64] uint4
    const float* __restrict__ bias,    // [2][1024]
    u16* __restrict__ gx2)             // [2*M][256][4] bf16
{
  constexpr int K = KS * 32;
  constexpr int PITCH = K + 8;        // u16; K=256->264 (528B, 16B-mult), K=512->520 (1040B, 16B-mult)
  __shared__ u16 As[64][PITCH];
  const int tid = threadIdx.x;
  const int l = tid & 63;
  const int w = tid >> 6;
  const int col = l & 15;
  const int quad = (l >> 4) & 3;
  const int m0 = blockIdx.x * 64;
  const int dir = blockIdx.y;

  // stage A: row lr = tid>>2, quarter lq = tid&3
  {
    const int lr = tid >> 2, lq = tid & 3;
    if constexpr (GATHER) {
      const float4* xrow = reinterpret_cast<const float4*>(
          (const float*)xsrc_v + (size_t)sent[m0 + lr] * 256) + lq * 16;
      u32* dst = reinterpret_cast<u32*>(&As[lr][lq * 64]);
#pragma unroll
      for (int i = 0; i < 16; ++i) {
        float4 v = xrow[i];
        dst[i * 2 + 0] = (u32)f2bf(v.x) | ((u32)f2bf(v.y) << 16);
        dst[i * 2 + 1] = (u32)f2bf(v.z) | ((u32)f2bf(v.w) << 16);
      }
    } else {
      const uint4* xrow = reinterpret_cast<const uint4*>(
          (const u16*)xsrc_v + (size_t)(m0 + lr) * 512) + lq * 16;
      uint4* dst = reinterpret_cast<uint4*>(&As[lr][lq * 128]);
#pragma unroll
      for (int i = 0; i < 16; ++i) dst[i] = xrow[i];
    }
  }
  __syncthreads();

  const uint4* wfd = wifrag + (size_t)dir * 16 * 4 * KS * 64;
#pragma unroll 1
  for (int nb = 0; nb < 16; ++nb) {
    uint4 bf[KS];
#pragma unroll
    for (int ks = 0; ks < KS; ++ks)
      bf[ks] = wfd[((nb * 4 + w) * KS + ks) * 64 + l];

    f32x4 acc[4];
#pragma unroll
    for (int mt = 0; mt < 4; ++mt) acc[mt] = (f32x4){0.f, 0.f, 0.f, 0.f};
#pragma unroll
    for (int ks = 0; ks < KS; ++ks) {
      short8 b8 = __builtin_bit_cast(short8, bf[ks]);
#pragma unroll
      for (int mt = 0; mt < 4; ++mt) {
        uint4 av = *reinterpret_cast<const uint4*>(&As[mt * 16 + col][ks * 32 + quad * 8]);
        acc[mt] = __builtin_amdgcn_mfma_f32_16x16x32_bf16(
            __builtin_bit_cast(short8, av), b8, acc[mt], 0, 0, 0);
      }
    }

    const int n = nb * 64 + w * 16 + col;
    const int gate = n >> 8, unit = n & 255;
    const float bv = bias[dir * 1024 + n];
#pragma unroll
    for (int mt = 0; mt < 4; ++mt) {
#pragma unroll
      for (int r = 0; r < 4; ++r) {
        int m = m0 + mt * 16 + quad * 4 + r;
        gx2[((size_t)(dir * Mn + m) * 256 + unit) * 4 + gate] = f2bf(acc[mt][r] + bv);
      }
    }
  }
}

// ---------------- MFMA recurrence v6: single-round concurrent spin, early h store --------------
__global__ __launch_bounds__(512, 2) void lstm_recur_mfma(
    const uint4* __restrict__ wfrag,  // [2][4][2048] uint4
    const u16* __restrict__ gx2,      // [2*Mn][256][4] bf16
    u64* __restrict__ hx,             // [8][4][512][256] u64
    u16* __restrict__ out)            // [B][S][512] bf16
{
  __shared__ uint4 Bs[8192];          // 128 KB: [ks][tau][lane]
  __shared__ u16 Ah[16][264];
  __shared__ f32x4 Pt[16][64];
  const int tid = threadIdx.x;
  const int l = tid & 63;
  const int w = tid >> 6;
  const int kh = w >> 2;
  const int ub = w & 3;
  const int g = blockIdx.x & 7;
  const int nq = blockIdx.x >> 3;
  const int dir = g >> 2, bg = g & 3;
  const int quad = (l >> 4) & 3;
  const int m0 = quad * 4;
  const int col = l & 15;
  const int uq = ub * 16 + col;
  const int u = nq * 64 + uq;

  {
    const uint4* wf = wfrag + ((size_t)(dir * 4 + nq)) * 2048;
#pragma unroll
    for (int i = 0; i < 16; ++i) Bs[tid + i * 512] = wf[tid + i * 512];
  }
  u64* mine = hx + ((size_t)(g * 4 + nq) * 512) * 256;
  float c[4] = {0.f, 0.f, 0.f, 0.f};

  // precompute remote-quarter addresses for the h exchange
  // load A: idx = tid (0..511): pq = tid>>8 in {0,1}; load B: idx = 512+tid (tid<256): pq = 2
  const int pqA = tid >> 8, offA = tid & 255;
  const int pqrA = pqA + (pqA >= nq ? 1 : 0);
  const int pqrB = 2 + (2 >= nq ? 1 : 0);
  const u64* baseA = hx + ((size_t)(g * 4 + pqrA) * 512) * 256 + offA;
  const u64* baseB = hx + ((size_t)(g * 4 + pqrB) * 512) * 256 + tid; // only tid<256
  const int unitA = offA >> 2, mgA = offA & 3;
  const int unitB = tid >> 2, mgB = tid & 3;

  __syncthreads();

  for (int s = 0; s < Sn; ++s) {
    const int t = dir ? (Sn - 1 - s) : s;

    uint2 gxv[4];
    if (kh == 0) {
#pragma unroll
      for (int r = 0; r < 4; ++r)
        gxv[r] = *reinterpret_cast<const uint2*>(
            gx2 + ((size_t)(dir * Mn + (bg * 16 + m0 + r) * Sn + t) * 256 + u) * 4);
    }

    f32x4 acc[4];
#pragma unroll
    for (int gi = 0; gi < 4; ++gi) acc[gi] = (f32x4){0.f, 0.f, 0.f, 0.f};

    if (s > 0) {
      // issue both remote loads concurrently (one coherent round-trip, not two)
      const u64* pA = baseA + (size_t)(s - 1) * 256;
      const u64* pB = baseB + (size_t)(s - 1) * 256;
      u64 va = __hip_atomic_load(pA, __ATOMIC_RELAXED, __HIP_MEMORY_SCOPE_AGENT);
      u64 vb = 0;
      if (tid < 256)
        vb = __hip_atomic_load(pB, __ATOMIC_RELAXED, __HIP_MEMORY_SCOPE_AGENT);

      while (va == ~0ULL)
        va = __hip_atomic_load(pA, __ATOMIC_RELAXED, __HIP_MEMORY_SCOPE_AGENT);
#pragma unroll
      for (int r = 0; r < 4; ++r)
        Ah[mgA * 4 + r][pqrA * 64 + unitA] = (u16)(va >> (r * 16));

      if (tid < 256) {
        while (vb == ~0ULL)
          vb = __hip_atomic_load(pB, __ATOMIC_RELAXED, __HIP_MEMORY_SCOPE_AGENT);
#pragma unroll
        for (int r = 0; r < 4; ++r)
          Ah[mgB * 4 + r][pqrB * 64 + unitB] = (u16)(vb >> (r * 16));
      }
    }
    __syncthreads();

    if (s > 0) {
#pragma unroll
      for (int ks2 = 0; ks2 < 4; ++ks2) {
        int ks = kh * 4 + ks2;
        uint4 av = *reinterpret_cast<const uint4*>(&Ah[col][ks * 32 + quad * 8]);
        short8 a8 = __builtin_bit_cast(short8, av);
#pragma unroll
        for (int gi = 0; gi < 4; ++gi)
          acc[gi] = __builtin_amdgcn_mfma_f32_16x16x32_bf16(
              a8, __builtin_bit_cast(short8, Bs[(ks * 16 + ub * 4 + gi) * 64 + l]), acc[gi], 0, 0, 0);
      }
      if (kh == 1)
#pragma unroll
        for (int gi = 0; gi < 4; ++gi) Pt[ub * 4 + gi][l] = acc[gi];
    }
    __syncthreads();

    if (kh == 0) {
      if (s > 0)
#pragma unroll
        for (int gi = 0; gi < 4; ++gi) acc[gi] += Pt[ub * 4 + gi][l];
      u16 hbf[4];
#pragma unroll
      for (int r = 0; r < 4; ++r) {
        float gi_ = acc[0][r] + b2f((u16)(gxv[r].x & 0xffff));
        float gf_ = acc[1][r] + b2f((u16)(gxv[r].x >> 16));
        float gg_ = acc[2][r] + b2f((u16)(gxv[r].y & 0xffff));
        float go_ = acc[3][r] + b2f((u16)(gxv[r].y >> 16));
        c[r] = sigf(gf_) * c[r] + sigf(gi_) * tanh_f(gg_);
        hbf[r] = f2bf(sigf(go_) * tanh_f(c[r]));
      }
      // fire the cross-block h store FIRST (critical path), then local/out writes
      u64 hpack = (u64)hbf[0] | ((u64)hbf[1] << 16) | ((u64)hbf[2] << 32) | ((u64)hbf[3] << 48);
      __hip_atomic_store(mine + (size_t)s * 256 + uq * 4 + quad, hpack,
                         __ATOMIC_RELAXED, __HIP_MEMORY_SCOPE_AGENT);
#pragma unroll
      for (int r = 0; r < 4; ++r) {
        Ah[m0 + r][u] = hbf[r];
        out[((size_t)(bg * 16 + m0 + r) * Sn + t) * HIDn + dir * Hn + u] = hbf[r];
      }
    }
  }
}

// ---------------- FC: one wave per (b,t), bf16 input rows ----------------
__global__ __launch_bounds__(64) void fc_kernel(const u16* __restrict__ out1,
                                                const float* __restrict__ fcw,
                                                const float* __restrict__ fcb,
                                                float* __restrict__ feats) {
  const int bs = blockIdx.x;
  const int l = threadIdx.x;
  const u16* row = out1 + (size_t)bs * HIDn;
  uint4 rv = *reinterpret_cast<const uint4*>(row + l * 8);
  float v[8];
  v[0] = bflo(rv.x); v[1] = bfhi(rv.x);
  v[2] = bflo(rv.y); v[3] = bfhi(rv.y);
  v[4] = bflo(rv.z); v[5] = bfhi(rv.z);
  v[6] = bflo(rv.w); v[7] = bfhi(rv.w);
#pragma unroll
  for (int tag = 0; tag < Tn; ++tag) {
    const float* w = fcw + tag * HIDn + l * 8;
    float4 w0 = *reinterpret_cast<const float4*>(w);
    float4 w1 = *reinterpret_cast<const float4*>(w + 4);
    float acc = v[0] * w0.x + v[1] * w0.y + v[2] * w0.z + v[3] * w0.w
              + v[4] * w1.x + v[5] * w1.y + v[6] * w1.z + v[7] * w1.w;
#pragma unroll
    for (int off = 32; off; off >>= 1) acc += __shfl_xor(acc, off);
    if (l == 0) feats[bs * Tn + tag] = acc + fcb[tag];
  }
}

// ---------------- CRF forward + gold, one wave per batch ----------------
__global__ __launch_bounds__(64) void crf_kernel(const float* __restrict__ feats,
                                                 const int* __restrict__ tags,
                                                 const int* __restrict__ lens,
                                                 const float* __restrict__ trans,
                                                 float* __restrict__ scores) {
  const int b = blockIdx.x;
  const int j = threadIdx.x;
  const int jj = j < Tn ? j : Tn - 1;
  const int len = lens[b];

  float trc[Tn];
#pragma unroll
  for (int i = 0; i < Tn; ++i) trc[i] = trans[i * Tn + jj];
  const float trS = trans[jj * Tn + STOP_T];

  float alpha = (j == START_T) ? 0.0f : NEGV;
  const float* fb = feats + (size_t)b * Sn * Tn;

  for (int t = 0; t < Sn; ++t) {
    float f = (j < Tn) ? fb[t * Tn + j] : 0.0f;
    float v[Tn];
    float m = -3.0e38f;
#pragma unroll
    for (int i = 0; i < Tn; ++i) {
      float ai = __shfl(alpha, i);
      v[i] = ai + trc[i];
      m = fmaxf(m, v[i]);
    }
    float ssum = 0.0f;
#pragma unroll
    for (int i = 0; i < Tn; ++i) ssum += __expf(v[i] - m);
    float newa = m + __logf(ssum) + f;
    if (t < len && j < Tn) alpha = newa;
  }

  float val = (j < Tn) ? alpha + trS : -3.0e38f;
  float m = val;
#pragma unroll
  for (int off = 32; off; off >>= 1) m = fmaxf(m, __shfl_xor(m, off));
  float se = (j < Tn) ? __expf(val - m) : 0.0f;
#pragma unroll
  for (int off = 32; off; off >>= 1) se += __shfl_xor(se, off);
  float fscore = m + __logf(se);

  const int* tg = tags + b * Sn;
  float part = 0.0f;
  for (int q = 0; q < 8; ++q) {
    int s0 = j * 8 + q;
    if (s0 < Sn - 1 && (s0 + 1) < len) {
      int ta = tg[s0], tb = tg[s0 + 1];
      part += trans[ta * Tn + tb] + fb[s0 * Tn + tb];
    }
  }
#pragma unroll
  for (int off = 32; off; off >>= 1) part += __shfl_xor(part, off);

  if (j == 0) {
    int t0 = tg[0];
    int tl = tg[len - 1];
    float gold = trans[START_T * Tn + t0] + fb[0 * Tn + t0] + part + trans[tl * Tn + STOP_T];
    scores[b] = fscore - gold;
  }
}

__global__ void finalize_kernel(const float* __restrict__ scores, float* __restrict__ out) {
  int l = threadIdx.x;
  float v = scores[l];
#pragma unroll
  for (int off = 32; off; off >>= 1) v += __shfl_xor(v, off);
  if (l == 0) out[0] = v / 64.0f;
}

extern "C" void kernel_launch(void* const* d_in, const int* in_sizes, int n_in,
                              void* d_out, int out_size, void* d_ws, size_t ws_size,
                              hipStream_t stream) {
  const int* sent = (const int*)d_in[0];
  const int* tags = (const int*)d_in[1];
  const int* lens = (const int*)d_in[2];
  const float* emb = (const float*)d_in[3];
  const float* wih0 = (const float*)d_in[4];
  const float* whh0 = (const float*)d_in[5];
  const float* bih0 = (const float*)d_in[6];
  const float* bhh0 = (const float*)d_in[7];
  const float* wih1 = (const float*)d_in[8];
  const float* whh1 = (const float*)d_in[9];
  const float* bih1 = (const float*)d_in[10];
  const float* bhh1 = (const float*)d_in[11];
  const float* fcw = (const float*)d_in[12];
  const float* fcb = (const float*)d_in[13];
  const float* trans = (const float*)d_in[14];

  // workspace (~206 MB)
  char* ws = (char*)d_ws;
  u16* outb = (u16*)ws;                                  // 33,554,432 B
  u16* gx2 = (u16*)(ws + 33554432);                      // 134,217,728 B
  float* feats = (float*)gx2;                            // aliases gx2 (dead before fc)
  char* p = ws + 33554432 + 134217728;
  u64* hx = (u64*)p;                    p += 33554432;   // [8][4][512][256] u64
  float* scores = (float*)p;            p += 256;
  float* bias0 = (float*)p;             p += 8192;
  float* bias1 = (float*)p;             p += 8192;
  u16* wifrag0 = (u16*)p;               p += 1048576;    // 524,288 u16
  u16* wifrag1 = (u16*)p;               p += 2097152;    // 1,048,576 u16
  u16* wfrag0 = (u16*)p;                p += 1048576;
  u16* wfrag1 = (u16*)p;                p += 1048576;

  prep_kernel<<<2048, 256, 0, stream>>>(wih0, whh0, bih0, bhh0, wih1, whh1, bih1, bhh1,
                                        wifrag0, wifrag1, wfrag0, wfrag1, bias0, bias1);

  dim3 ggrid(Mn / 64, 2);
  hipMemsetAsync(hx, 0xFF, 33554432, stream);
  gemm_ih<8, true><<<ggrid, 256, 0, stream>>>(emb, sent, (const uint4*)wifrag0, bias0, gx2);
  lstm_recur_mfma<<<32, 512, 0, stream>>>((const uint4*)wfrag0, gx2, hx, outb);
  hipMemsetAsync(hx, 0xFF, 33554432, stream);
  gemm_ih<16, false><<<ggrid, 256, 0, stream>>>(outb, nullptr, (const uint4*)wifrag1, bias1, gx2);
  lstm_recur_mfma<<<32, 512, 0, stream>>>((const uint4*)wfrag1, gx2, hx, outb);

  fc_kernel<<<Mn, 64, 0, stream>>>(outb, fcw, fcb, feats);
  crf_kernel<<<Bn, 64, 0, stream>>>(feats, tags, lens, trans, scores);
  finalize_kernel<<<1, 64, 0, stream>>>(scores, (float*)d_out);
}